// Round 8
// baseline (701.696 us; speedup 1.0000x reference)
//
#include <hip/hip_runtime.h>
#include <stdint.h>

// Baum-Welch forward-backward posteriors (log_gamma), MI355X gfx950.
//
// R11 -> R12: one barrier per step (deferred scale), bf16 staging, direct
// register->global output stores.
//  - R11 residue: 2350 cy/step, ~55% stall; chain = MFMA -> B1 -> smax read
//    -> scale -> xfrag+rbuf write -> B2 -> rbuf flush read. Two LDS
//    round-trips + 3.1M bank conflicts (rbuf 8-way write aliasing).
//  - Deferred exact scale: rs_t = rcp(max y_{t-1}), read from smax written
//    LAST step (self-correcting: max y oscillates with emission magnitude
//    in e^[-25,0], no random walk). smax exchange moves off the critical
//    path -> B1 deleted.
//  - bf16 staging (range e^±88) makes the deferred scale safe (fp16 would
//    underflow at e^-20). bf16 MFMA = same rate as fp16.
//  - rbuf deleted: outputs stored register->global directly (each wave
//    covers full 64B lines per seq; stores stay in flight, never drained
//    in-loop). Packed bf16 words reused for xfrag ds_write AND the global
//    alpha/beta store (ws buffers bf16, 67MB each; gamma pass reads bf16).
//  - Per step: ds_read xfrag -> MFMA -> mul/pack -> ds_write + stores ->
//    ONE lgkm-only barrier.

#define NB 256
#define TT 512
#define KK 256
#define VV 4096
#define SPB 16            // sequences per block
#define NBLK (NB / SPB)   // 16 recurrence blocks per direction
#define LOG2E 1.44269504088896f
#define LN2 0.693147180559945f

typedef float f4 __attribute__((ext_vector_type(4)));
typedef short b8 __attribute__((ext_vector_type(8)));
typedef unsigned int u32;
typedef u32 u2v __attribute__((ext_vector_type(2)));
typedef u32 u4v __attribute__((ext_vector_type(4)));

struct SmemT {
  unsigned short obs_s[SPB][520];  // 16.6 KB (stride 520: 2 lanes/bank)
  b8 xfrag[2][8][64];              // 16 KB ping-pong staged B fragments
  float smax[2][160];              // ping-pong per-(seq,wave) max partials
};

__device__ __forceinline__ void bar_lds() {
  asm volatile("s_waitcnt lgkmcnt(0)" ::: "memory");
  __builtin_amdgcn_s_barrier();
}

__device__ __forceinline__ unsigned short f2bf_rne(float x) {
  u32 u = __float_as_uint(x);
  return (unsigned short)((u + 0x7FFFu + ((u >> 16) & 1u)) >> 16);
}
// pack two positive floats to 2xbf16 (round-half-up) in one v_perm each.
__device__ __forceinline__ u32 pkbf(float lo, float hi) {
  return __builtin_amdgcn_perm(__float_as_uint(hi) + 0x8000u,
                               __float_as_uint(lo) + 0x8000u, 0x07060302u);
}
__device__ __forceinline__ u2v mku2(u32 a, u32 b) {
  u2v v; v[0] = a; v[1] = b; return v;
}

// MODE 0: forward.  H16: bf16 alpha rows -> outh; else f32 rows -> gout.
// MODE 1: backward fused-gamma (sequential tier): reads f32 alpha from gout,
//         overwrites rows 510..0 with f32 alpha*beta (row 511 stays alpha).
// MODE 2: backward, bf16 scaled-beta rows -> outh (row 511 = 1).
template <int MODE, bool TRANS, bool H16>
__device__ __forceinline__ void hmm_body(
    SmemT& sm, int blk, const float* __restrict__ lpi,
    const float* __restrict__ lA, const float* __restrict__ lB,
    const float* __restrict__ ebT, const int* __restrict__ obs,
    float* __restrict__ gout, unsigned short* __restrict__ outh) {
  const int n0 = blk * SPB;
  const int tid = threadIdx.x;
  const int w = tid >> 6;  // wave 0..7: output states [32w, 32w+32)
  const int l = tid & 63;
  const int n = l & 15;    // sequence slot (also A-operand m-slot)
  const int q = l >> 4;    // 0..3
  const int j0 = 32 * w + 4 * q;  // lane's states: j0..j0+3, j0+16..j0+19

  for (int i = tid; i < SPB * TT; i += 512)
    sm.obs_s[i >> 9][i & 511] = (unsigned short)obs[(size_t)n0 * TT + i];

  // Static bf16 A fragments (R10/R11-verified map): m = l&15,
  // k = kc*32 + q*8 + e. fwd: expA[k][m] (A^T); bwd: expA[m][k] (A).
  b8 afrag[2][8];
#pragma unroll
  for (int mt = 0; mt < 2; ++mt) {
    const int m = (2 * w + mt) * 16 + n;
#pragma unroll
    for (int kc = 0; kc < 8; ++kc) {
      u4v tmp;
#pragma unroll
      for (int ep = 0; ep < 4; ++ep) {
        const int k = kc * 32 + q * 8 + 2 * ep;
        float v0, v1;
        if (MODE == 0) {
          v0 = lA[(size_t)k * KK + m];
          v1 = lA[(size_t)(k + 1) * KK + m];
        } else {
          v0 = lA[(size_t)m * KK + k];
          v1 = lA[(size_t)m * KK + k + 1];
        }
        v0 = exp2f(v0 * LOG2E);
        v1 = exp2f(v1 * LOG2E);
        tmp[ep] = (u32)f2bf_rne(v0) | ((u32)f2bf_rne(v1) << 16);
      }
      afrag[mt][kc] = __builtin_bit_cast(b8, tmp);
    }
  }

  // Fragment-staging target for value (state j, seq n): chunk kc = w,
  // line 32*mt + 16*(q>>1) + n, ushort elems 4*(q&1)+reg. (R10-verified.)
  const int lam0 = (q >> 1) * 16 + n;
  const int e0 = (q & 1) * 4;

  __syncthreads();  // obs_s ready

  auto emis = [&](int te, f4& ea, f4& eb) {
    const int o = sm.obs_s[n][te];
    if constexpr (TRANS) {
      const float* er = ebT + (size_t)o * KK + j0;
      ea = *(const f4*)er;
      eb = *(const f4*)(er + 16);
    } else {
#pragma unroll
      for (int r = 0; r < 4; ++r) {
        ea[r] = exp2f(lB[(size_t)(j0 + r) * VV + o] * LOG2E);
        eb[r] = exp2f(lB[(size_t)(j0 + 16 + r) * VV + o] * LOG2E);
      }
    }
  };

  // Write staged fragments + per-seq max partials for NEXT step's scale.
  auto stage_write = [&](const u32 p[4], const float yv[8], int dst) {
    *(u2v*)((unsigned short*)&sm.xfrag[dst][w][lam0] + e0) = mku2(p[0], p[1]);
    *(u2v*)((unsigned short*)&sm.xfrag[dst][w][lam0 + 32] + e0) =
        mku2(p[2], p[3]);
    float m = fmaxf(fmaxf(fmaxf(yv[0], yv[1]), fmaxf(yv[2], yv[3])),
                    fmaxf(fmaxf(yv[4], yv[5]), fmaxf(yv[6], yv[7])));
    m = fmaxf(m, __shfl_xor(m, 16));
    m = fmaxf(m, __shfl_xor(m, 32));
    if (l < 16) sm.smax[dst][l * 9 + w] = m;
  };

  auto mfma_step = [&](int cur, f4& o0, f4& o1) {
    b8 bfr[8];
#pragma unroll
    for (int kc = 0; kc < 8; ++kc) bfr[kc] = sm.xfrag[cur][kc][l];
    f4 a0a = {0.f, 0.f, 0.f, 0.f}, a0b = a0a, a1a = a0a, a1b = a0a;
#pragma unroll
    for (int kc = 0; kc < 4; ++kc) {
      a0a = __builtin_amdgcn_mfma_f32_16x16x32_bf16(afrag[0][kc], bfr[kc],
                                                    a0a, 0, 0, 0);
      a1a = __builtin_amdgcn_mfma_f32_16x16x32_bf16(afrag[1][kc], bfr[kc],
                                                    a1a, 0, 0, 0);
    }
#pragma unroll
    for (int kc = 4; kc < 8; ++kc) {
      a0b = __builtin_amdgcn_mfma_f32_16x16x32_bf16(afrag[0][kc], bfr[kc],
                                                    a0b, 0, 0, 0);
      a1b = __builtin_amdgcn_mfma_f32_16x16x32_bf16(afrag[1][kc], bfr[kc],
                                                    a1b, 0, 0, 0);
    }
    o0 = a0a + a0b;
    o1 = a1a + a1b;
  };

  auto rscale = [&](int cur) -> float {
    float mm = sm.smax[cur][n * 9];
#pragma unroll
    for (int ww = 1; ww < 8; ++ww) mm = fmaxf(mm, sm.smax[cur][n * 9 + ww]);
    return __builtin_amdgcn_rcpf(fmaxf(mm, 1e-30f));
  };

  if (MODE == 0) {
    // ---- forward ----
    f4 ea, eb;
    emis(0, ea, eb);
    float y0[8];
#pragma unroll
    for (int r = 0; r < 8; ++r) {
      const int jr = j0 + 16 * (r >> 2) + (r & 3);
      y0[r] = exp2f(lpi[jr] * LOG2E) * ((r < 4) ? ea[r] : eb[r - 4]);
    }
    u32 p[4] = {pkbf(y0[0], y0[1]), pkbf(y0[2], y0[3]), pkbf(y0[4], y0[5]),
                pkbf(y0[6], y0[7])};
    stage_write(p, y0, 0);
    if (H16) {
      unsigned short* op = outh + ((size_t)(n0 + n) * TT + 0) * KK + j0;
      *(u2v*)op = mku2(p[0], p[1]);
      *(u2v*)(op + 16) = mku2(p[2], p[3]);
    } else {
      float* op = gout + ((size_t)(n0 + n) * TT + 0) * KK + j0;
      f4 v0, v1;
#pragma unroll
      for (int r = 0; r < 4; ++r) { v0[r] = y0[r]; v1[r] = y0[4 + r]; }
      *(f4*)op = v0;
      *(f4*)(op + 16) = v1;
    }
    bar_lds();
    f4 eca, ecb;
    emis(1, eca, ecb);

#pragma unroll 1
    for (int t = 0; t < TT - 1; ++t) {
      const int cur = t & 1;
      f4 pa, pb;
      emis(t + 2 < TT ? t + 2 : TT - 1, pa, pb);  // prefetch o_{t+2}
      const float rs = rscale(cur);               // deferred (last step's max)
      f4 acc0, acc1;
      mfma_step(cur, acc0, acc1);
      float yv[8];
#pragma unroll
      for (int r = 0; r < 8; ++r) {
        const float e = (r < 4) ? eca[r] : ecb[r - 4];
        const float D = (r < 4) ? acc0[r] : acc1[r - 4];
        yv[r] = D * e * rs;  // scaled alpha_{t+1}
      }
      u32 pp[4] = {pkbf(yv[0], yv[1]), pkbf(yv[2], yv[3]), pkbf(yv[4], yv[5]),
                   pkbf(yv[6], yv[7])};
      stage_write(pp, yv, cur ^ 1);
      if (H16) {
        unsigned short* op = outh + ((size_t)(n0 + n) * TT + t + 1) * KK + j0;
        *(u2v*)op = mku2(pp[0], pp[1]);
        *(u2v*)(op + 16) = mku2(pp[2], pp[3]);
      } else {
        float* op = gout + ((size_t)(n0 + n) * TT + t + 1) * KK + j0;
        f4 v0, v1;
#pragma unroll
        for (int r = 0; r < 4; ++r) { v0[r] = yv[r]; v1[r] = yv[4 + r]; }
        *(f4*)op = v0;
        *(f4*)(op + 16) = v1;
      }
      bar_lds();
      eca = pa;
      ecb = pb;
    }
  } else {
    // ---- backward (MODE1: fused f32 gamma; MODE2: bf16 beta rows) ----
    f4 ea, eb;
    emis(TT - 1, ea, eb);
    float y0[8];
#pragma unroll
    for (int r = 0; r < 8; ++r) y0[r] = (r < 4) ? ea[r] : eb[r - 4];  // w_511
    u32 p[4] = {pkbf(y0[0], y0[1]), pkbf(y0[2], y0[3]), pkbf(y0[4], y0[5]),
                pkbf(y0[6], y0[7])};
    stage_write(p, y0, 0);
    if (MODE == 2) {  // beta row 511 = 1
      const u32 one2 = 0x3F803F80u;
      unsigned short* op = outh + ((size_t)(n0 + n) * TT + (TT - 1)) * KK + j0;
      *(u2v*)op = mku2(one2, one2);
      *(u2v*)(op + 16) = mku2(one2, one2);
    }
    bar_lds();
    f4 eca, ecb;
    emis(TT - 2, eca, ecb);
    f4 aa = {0.f, 0.f, 0.f, 0.f}, ab = aa;
    if (MODE == 1) {
      const float* ar = gout + ((size_t)(n0 + n) * TT + (TT - 2)) * KK + j0;
      aa = *(const f4*)ar;
      ab = *(const f4*)(ar + 16);
    }

#pragma unroll 1
    for (int t = TT - 2; t >= 0; --t) {
      const int cur = (TT - 2 - t) & 1;
      const int tp = t > 0 ? t - 1 : 0;
      f4 pa, pb;
      emis(tp, pa, pb);  // prefetch o_{t-1}
      f4 naa = {0.f, 0.f, 0.f, 0.f}, nab = naa;
      if (MODE == 1 && t > 0) {
        const float* ar = gout + ((size_t)(n0 + n) * TT + tp) * KK + j0;
        naa = *(const f4*)ar;
        nab = *(const f4*)(ar + 16);
      }
      const float rs = rscale(cur);
      f4 acc0, acc1;
      mfma_step(cur, acc0, acc1);  // scaled beta_t
      float yv[8];
#pragma unroll
      for (int r = 0; r < 8; ++r) {
        const float bvr = (r < 4) ? acc0[r] : acc1[r - 4];
        const float e = (r < 4) ? eca[r] : ecb[r - 4];
        yv[r] = bvr * e * rs;  // staged w_t
      }
      u32 pp[4] = {pkbf(yv[0], yv[1]), pkbf(yv[2], yv[3]), pkbf(yv[4], yv[5]),
                   pkbf(yv[6], yv[7])};
      stage_write(pp, yv, cur ^ 1);
      if (MODE == 2) {
        const u32 q0 = pkbf(acc0[0] * rs, acc0[1] * rs);
        const u32 q1 = pkbf(acc0[2] * rs, acc0[3] * rs);
        const u32 q2 = pkbf(acc1[0] * rs, acc1[1] * rs);
        const u32 q3 = pkbf(acc1[2] * rs, acc1[3] * rs);
        unsigned short* op = outh + ((size_t)(n0 + n) * TT + t) * KK + j0;
        *(u2v*)op = mku2(q0, q1);
        *(u2v*)(op + 16) = mku2(q2, q3);
      } else {
        f4 g0, g1;
#pragma unroll
        for (int r = 0; r < 4; ++r) {
          g0[r] = aa[r] * acc0[r];
          g1[r] = ab[r] * acc1[r];
        }
        float* op = gout + ((size_t)(n0 + n) * TT + t) * KK + j0;
        *(f4*)op = g0;
        *(f4*)(op + 16) = g1;
      }
      bar_lds();
      eca = pa;
      ecb = pb;
      aa = naa;
      ab = nab;
    }
  }
}

// Concurrent tier: blocks [0,16) fwd -> aws (bf16), [16,32) bwd -> bws (bf16).
__global__ __launch_bounds__(512, 1) void hmm_comb16(
    const float* __restrict__ lpi, const float* __restrict__ lA,
    const float* __restrict__ lB, const float* __restrict__ ebT,
    const int* __restrict__ obs, unsigned short* __restrict__ aws,
    unsigned short* __restrict__ bws) {
  __shared__ SmemT sm;
  if (blockIdx.x < NBLK)
    hmm_body<0, true, true>(sm, blockIdx.x, lpi, lA, lB, ebT, obs, nullptr,
                            aws);
  else
    hmm_body<2, true, true>(sm, blockIdx.x - NBLK, lpi, lA, lB, ebT, obs,
                            nullptr, bws);
}

// Sequential tiers (f32 rows in gout).
template <int MODE, bool TRANS>
__global__ __launch_bounds__(512, 1) void hmm_one(
    const float* __restrict__ lpi, const float* __restrict__ lA,
    const float* __restrict__ lB, const float* __restrict__ ebT,
    const int* __restrict__ obs, float* __restrict__ gout) {
  __shared__ SmemT sm;
  hmm_body<MODE, TRANS, false>(sm, blockIdx.x, lpi, lA, lB, ebT, obs, gout,
                               nullptr);
}

// ebT[v][k] = exp(lB[k][v]). 4MB.
__global__ __launch_bounds__(256) void expT(const float* __restrict__ lB,
                                            float* __restrict__ ebT) {
#pragma unroll 1
  for (int v = blockIdx.x; v < VV; v += gridDim.x)
    for (int k = threadIdx.x; k < KK; k += 256)
      ebT[(size_t)v * KK + k] = exp2f(lB[(size_t)k * VV + v] * LOG2E);
}

// Concurrent tier pass 3: gamma = bf16 alpha * bf16 beta, log-normalized f32.
__global__ __launch_bounds__(256) void gamma_mul16(
    float* __restrict__ gout, const unsigned short* __restrict__ aw,
    const unsigned short* __restrict__ bw) {
  const int wave = blockIdx.x * 4 + (threadIdx.x >> 6);
  const int c = threadIdx.x & 63;
  const int stride = gridDim.x * 4;
#pragma unroll 1
  for (int row = wave; row < NB * TT; row += stride) {
    const size_t base = (size_t)row * KK + c * 4;
    const u2v ua = *(const u2v*)(aw + base);
    const u2v ub = *(const u2v*)(bw + base);
    f4 v;
    v[0] = __uint_as_float(ua[0] << 16) * __uint_as_float(ub[0] << 16);
    v[1] = __uint_as_float(ua[0] & 0xFFFF0000u) *
           __uint_as_float(ub[0] & 0xFFFF0000u);
    v[2] = __uint_as_float(ua[1] << 16) * __uint_as_float(ub[1] << 16);
    v[3] = __uint_as_float(ua[1] & 0xFFFF0000u) *
           __uint_as_float(ub[1] & 0xFFFF0000u);
#pragma unroll
    for (int r = 0; r < 4; ++r) v[r] = fmaxf(v[r], 1e-37f);
    float s = (v[0] + v[1]) + (v[2] + v[3]);
#pragma unroll
    for (int d = 1; d < 64; d <<= 1) s += __shfl_xor(s, d);
    const float lg = __log2f(s);
    f4 o;
    o[0] = (__log2f(v[0]) - lg) * LN2;
    o[1] = (__log2f(v[1]) - lg) * LN2;
    o[2] = (__log2f(v[2]) - lg) * LN2;
    o[3] = (__log2f(v[3]) - lg) * LN2;
    *(f4*)(gout + base) = o;
  }
}

// Sequential tier pass 3: rows already hold f32 alpha*beta; log-normalize.
__global__ __launch_bounds__(256) void gamma_norm(float* __restrict__ gout) {
  const int wave = blockIdx.x * 4 + (threadIdx.x >> 6);
  const int c = threadIdx.x & 63;
  const int stride = gridDim.x * 4;
#pragma unroll 1
  for (int row = wave; row < NB * TT; row += stride) {
    float* p = gout + (size_t)row * KK + c * 4;
    const f4 v = *(const f4*)p;
    float s = (v[0] + v[1]) + (v[2] + v[3]);
#pragma unroll
    for (int d = 1; d < 64; d <<= 1) s += __shfl_xor(s, d);
    const float lg = __log2f(s);
    f4 o;
    o[0] = (__log2f(v[0]) - lg) * LN2;
    o[1] = (__log2f(v[1]) - lg) * LN2;
    o[2] = (__log2f(v[2]) - lg) * LN2;
    o[3] = (__log2f(v[3]) - lg) * LN2;
    *(f4*)p = o;
  }
}

extern "C" void kernel_launch(void* const* d_in, const int* in_sizes, int n_in,
                              void* d_out, int out_size, void* d_ws, size_t ws_size,
                              hipStream_t stream) {
  const float* lpi = (const float*)d_in[0];
  const float* lA = (const float*)d_in[1];
  const float* lB = (const float*)d_in[2];
  const int* obs = (const int*)d_in[3];
  float* gout = (float*)d_out;

  const size_t EBT_B = (size_t)VV * KK * sizeof(float);           // 4 MB
  const size_t H16_B = (size_t)NB * TT * KK * sizeof(short);      // 67 MB
  float* ebT = (float*)d_ws;
  unsigned short* aws = (unsigned short*)((char*)d_ws + EBT_B);
  unsigned short* bws = (unsigned short*)((char*)d_ws + EBT_B + H16_B);

  if (ws_size >= EBT_B + 2 * H16_B) {
    expT<<<2048, 256, 0, stream>>>(lB, ebT);
    hmm_comb16<<<2 * NBLK, 512, 0, stream>>>(lpi, lA, lB, ebT, obs, aws, bws);
    gamma_mul16<<<2048, 256, 0, stream>>>(gout, aws, bws);
  } else if (ws_size >= EBT_B) {
    expT<<<2048, 256, 0, stream>>>(lB, ebT);
    hmm_one<0, true><<<NBLK, 512, 0, stream>>>(lpi, lA, lB, ebT, obs, gout);
    hmm_one<1, true><<<NBLK, 512, 0, stream>>>(lpi, lA, lB, ebT, obs, gout);
    gamma_norm<<<2048, 256, 0, stream>>>(gout);
  } else {
    hmm_one<0, false><<<NBLK, 512, 0, stream>>>(lpi, lA, lB, nullptr, obs, gout);
    hmm_one<1, false><<<NBLK, 512, 0, stream>>>(lpi, lA, lB, nullptr, obs, gout);
    gamma_norm<<<2048, 256, 0, stream>>>(gout);
  }
}

// Round 9
// 691.251 us; speedup vs baseline: 1.0151x; 1.0151x over previous
//
#include <hip/hip_runtime.h>
#include <stdint.h>

// Baum-Welch forward-backward posteriors (log_gamma), MI355X gfx950.
//
// R12 -> R13: shrink the per-step chain (all R5-R12 variants sat at
// ~2300-2700 cy/step regardless of structure).
//  - 4-wave blocks (256 thr, 1 wave/SIMD, 512-VGPR budget): A = 4 m-tiles
//    per wave (128 VGPR). LDS fragment reads halve (32KB/step), VALU issue
//    no longer 2-wave serialized, barrier syncs 4 waves.
//  - Deferred-by-2 per-seq scale: smax written slot cur / read slot cur^1;
//    the cross-lane max + LDS write run POST-barrier in the next step's
//    shadow. 2-step drift bounded (e^±52) -> bf16 staging safe.
//  - Deferred global stores: step t's packed row stored at top of region
//    t+1 (overlaps ds_read/MFMA wait).
//  - Depth-2 emission prefetch (use-then-reload named buffers; unroll x2
//    with literal CUR via macros -> no runtime-indexed register arrays).
//  - R12's proven 8-wave kernels kept verbatim as ws-fallback tiers.

#define NB 256
#define TT 512
#define KK 256
#define VV 4096
#define SPB 16            // sequences per block
#define NBLK (NB / SPB)   // 16 recurrence blocks per direction
#define LOG2E 1.44269504088896f
#define LN2 0.693147180559945f

typedef float f4 __attribute__((ext_vector_type(4)));
typedef short b8 __attribute__((ext_vector_type(8)));
typedef unsigned int u32;
typedef u32 u2v __attribute__((ext_vector_type(2)));
typedef u32 u4v __attribute__((ext_vector_type(4)));

__device__ __forceinline__ void bar_lds() {
  asm volatile("s_waitcnt lgkmcnt(0)" ::: "memory");
  __builtin_amdgcn_s_barrier();
}

__device__ __forceinline__ unsigned short f2bf_rne(float x) {
  u32 u = __float_as_uint(x);
  return (unsigned short)((u + 0x7FFFu + ((u >> 16) & 1u)) >> 16);
}
// pack two positive floats to 2xbf16 (round-half-up) in one v_perm each.
__device__ __forceinline__ u32 pkbf(float lo, float hi) {
  return __builtin_amdgcn_perm(__float_as_uint(hi) + 0x8000u,
                               __float_as_uint(lo) + 0x8000u, 0x07060302u);
}
__device__ __forceinline__ u2v mku2(u32 a, u32 b) {
  u2v v; v[0] = a; v[1] = b; return v;
}
__device__ __forceinline__ float fmax4(const f4& v) {
  return fmaxf(fmaxf(v[0], v[1]), fmaxf(v[2], v[3]));
}

// ======================= NEW 4-wave MFMA recurrence =======================
// MODE 0: forward, bf16 scaled-alpha rows -> outh.
// MODE 2: backward, bf16 scaled-beta rows -> outh (row 511 = 1).
struct Sm4 {
  unsigned short obs4[SPB][520];           // 16.6 KB
  b8 xfrag[2][8][64];                      // 16 KB ping-pong B fragments
  __align__(16) float smax[2][16][4];      // deferred per-seq max partials
};

template <int MODE>
__device__ __forceinline__ void body4(Sm4& sm, int blk,
                                      const float* __restrict__ lpi,
                                      const float* __restrict__ lA,
                                      const float* __restrict__ ebT,
                                      const int* __restrict__ obs,
                                      unsigned short* __restrict__ outh) {
  const int n0 = blk * SPB;
  const int tid = threadIdx.x;  // 0..255
  const int w = tid >> 6;       // wave 0..3: owns states [64w, 64w+64)
  const int l = tid & 63;
  const int n = l & 15;         // sequence slot
  const int q = l >> 4;         // 0..3
  const int jo0 = 64 * w + 4 * q;  // tile mt: states jo0+16*mt .. +3

  for (int i = tid; i < SPB * TT; i += 256)
    sm.obs4[i >> 9][i & 511] = (unsigned short)obs[(size_t)n0 * TT + i];

  // A fragments: 4 m-tiles (tile = 4w+mt), m = 16*tile + n,
  // k = kc*32 + q*8 + e.  fwd: expA[k][m]; bwd: expA[m][k].
  b8 af[4][8];
#pragma unroll
  for (int mt = 0; mt < 4; ++mt) {
    const int m = 16 * (4 * w + mt) + n;
#pragma unroll
    for (int kc = 0; kc < 8; ++kc) {
      u4v tmp;
#pragma unroll
      for (int ep = 0; ep < 4; ++ep) {
        const int k = kc * 32 + q * 8 + 2 * ep;
        float v0, v1;
        if (MODE == 0) {
          v0 = lA[(size_t)k * KK + m];
          v1 = lA[(size_t)(k + 1) * KK + m];
        } else {
          v0 = lA[(size_t)m * KK + k];
          v1 = lA[(size_t)m * KK + k + 1];
        }
        tmp[ep] = pkbf(exp2f(v0 * LOG2E), exp2f(v1 * LOG2E));
      }
      af[mt][kc] = __builtin_bit_cast(b8, tmp);
    }
  }

  // Staging target for tile mt (R10-verified map, 4-wave form):
  // plane kc = tile>>1; ushort index = 8*(n + 16*(q>>1) + 32*(tile&1))
  //                                    + 4*(q&1).
  int usb[4];
#pragma unroll
  for (int mt = 0; mt < 4; ++mt) {
    const int tile = 4 * w + mt;
    usb[mt] = 8 * (n + 16 * (q >> 1) + 32 * (tile & 1)) + 4 * (q & 1);
  }
  const int kcp[4] = {(4 * w) >> 1, (4 * w) >> 1, (4 * w + 2) >> 1,
                      (4 * w + 2) >> 1};

  if (tid < 128) ((float*)sm.smax)[tid] = 1.0f;  // seed both slots
  __syncthreads();  // obs4 + seeds ready

  const size_t rb = (size_t)n0 * TT * KK;  // + n*TT*KK later
  const size_t rown = (size_t)(n0 + n) * TT * KK;
  u32 pst[8];   // deferred packed output row (fwd: alpha; bwd: beta)
  float mloc;   // this step's in-lane max (cross-lane done next region)
  f4 eA[4], eB[4];
  (void)rb;

  auto emis4 = [&](int o, f4 e[4]) {
    const float* er = ebT + (size_t)o * KK + jo0;
#pragma unroll
    for (int mt = 0; mt < 4; ++mt) e[mt] = *(const f4*)(er + 16 * mt);
  };

  // One MFMA step: acc[mt] from xfrag[cur].
#define MFMA4(CUR, ACC)                                                     \
  {                                                                         \
    b8 bfr[8];                                                              \
    _Pragma("unroll") for (int kc = 0; kc < 8; ++kc) bfr[kc] =              \
        sm.xfrag[CUR][kc][l];                                               \
    _Pragma("unroll") for (int mt = 0; mt < 4; ++mt) {                      \
      f4 ca = {0.f, 0.f, 0.f, 0.f}, cb = ca;                                \
      _Pragma("unroll") for (int kc = 0; kc < 4; ++kc) ca =                 \
          __builtin_amdgcn_mfma_f32_16x16x32_bf16(af[mt][kc], bfr[kc], ca,  \
                                                  0, 0, 0);                 \
      _Pragma("unroll") for (int kc = 4; kc < 8; ++kc) cb =                 \
          __builtin_amdgcn_mfma_f32_16x16x32_bf16(af[mt][kc], bfr[kc], cb,  \
                                                  0, 0, 0);                 \
      ACC[mt] = ca + cb;                                                    \
    }                                                                       \
  }

#define SHADOW(CUR, ROW)                                                    \
  { /* deferred store of prev packed row + deferred smax combine */         \
    unsigned short* op_ = outh + rown + (size_t)(ROW)*KK + jo0;             \
    _Pragma("unroll") for (int mt = 0; mt < 4; ++mt)                        \
        *(u2v*)(op_ + 16 * mt) = mku2(pst[2 * mt], pst[2 * mt + 1]);        \
    float mm_ = fmaxf(mloc, __shfl_xor(mloc, 16));                          \
    mm_ = fmaxf(mm_, __shfl_xor(mm_, 32));                                  \
    if (l < 16) sm.smax[CUR][n][w] = mm_;                                   \
  }

#define RSCALE(CUR, RS)                                                     \
  const f4 sm4_ = *(const f4*)&sm.smax[(CUR) ^ 1][n][0];                    \
  const float RS = __builtin_amdgcn_rcpf(fmaxf(fmax4(sm4_), 1e-30f));

#define STAGE(CUR, P)                                                       \
  _Pragma("unroll") for (int mt = 0; mt < 4; ++mt)                          \
      *(u2v*)((unsigned short*)&sm.xfrag[(CUR) ^ 1][kcp[mt]][0] +           \
              usb[mt]) = mku2(P[2 * mt], P[2 * mt + 1]);

  if (MODE == 0) {
    // ---------------- forward ----------------
    {
      const int o0 = sm.obs4[n][0];
      f4 e[4];
      emis4(o0, e);
      mloc = 0.f;
#pragma unroll
      for (int mt = 0; mt < 4; ++mt) {
        const f4 pi4 = *(const f4*)(lpi + jo0 + 16 * mt);
        f4 u;
#pragma unroll
        for (int r = 0; r < 4; ++r) u[r] = exp2f(pi4[r] * LOG2E) * e[mt][r];
        pst[2 * mt] = pkbf(u[0], u[1]);
        pst[2 * mt + 1] = pkbf(u[2], u[3]);
        mloc = fmaxf(mloc, fmax4(u));
      }
      STAGE(1, pst);  // write xfrag[0] ( (1)^1 = 0 )
      emis4(sm.obs4[n][1], eA);
      emis4(sm.obs4[n][2], eB);
      bar_lds();
    }

#define STEPF(T, CUR, EU)                                                   \
  {                                                                         \
    const int t_ = (T);                                                     \
    SHADOW(CUR, t_)                                                         \
    RSCALE(CUR, rs_)                                                        \
    const f4 ec0 = EU[0], ec1 = EU[1], ec2 = EU[2], ec3 = EU[3];            \
    const int o3_ = sm.obs4[n][t_ + 3 < TT ? t_ + 3 : TT - 1];              \
    emis4(o3_, EU);                                                         \
    f4 acc[4];                                                              \
    MFMA4(CUR, acc)                                                         \
    const f4 ecs[4] = {ec0, ec1, ec2, ec3};                                 \
    mloc = 0.f;                                                             \
    _Pragma("unroll") for (int mt = 0; mt < 4; ++mt) {                      \
      const f4 y = acc[mt] * (ecs[mt] * rs_);                               \
      pst[2 * mt] = pkbf(y[0], y[1]);                                       \
      pst[2 * mt + 1] = pkbf(y[2], y[3]);                                   \
      mloc = fmaxf(mloc, fmax4(y));                                         \
    }                                                                       \
    STAGE(CUR, pst)                                                         \
    bar_lds();                                                              \
  }

#pragma unroll 1
    for (int t = 0; t < TT - 2; t += 2) {
      STEPF(t, 0, eA)
      STEPF(t + 1, 1, eB)
    }
    STEPF(TT - 2, 0, eA)  // t = 510
    {                     // final deferred row 511
      unsigned short* op = outh + rown + (size_t)(TT - 1) * KK + jo0;
#pragma unroll
      for (int mt = 0; mt < 4; ++mt)
        *(u2v*)(op + 16 * mt) = mku2(pst[2 * mt], pst[2 * mt + 1]);
    }
#undef STEPF
  } else {
    // ---------------- backward (beta rows to outh) ----------------
    u32 qst[8];
    {
      const int oL = sm.obs4[n][TT - 1];
      f4 e[4];
      emis4(oL, e);
      mloc = 0.f;
      u32 pw[8];
#pragma unroll
      for (int mt = 0; mt < 4; ++mt) {
        pw[2 * mt] = pkbf(e[mt][0], e[mt][1]);
        pw[2 * mt + 1] = pkbf(e[mt][2], e[mt][3]);
        mloc = fmaxf(mloc, fmax4(e[mt]));
        qst[2 * mt] = 0x3F803F80u;  // beta_511 = 1 (2xbf16 1.0)
        qst[2 * mt + 1] = 0x3F803F80u;
      }
      STAGE(1, pw)  // staged w_511 into xfrag[0]
      emis4(sm.obs4[n][TT - 2], eA);
      emis4(sm.obs4[n][TT - 3], eB);
      bar_lds();
    }

#define STEPB(S, CUR, EU)                                                   \
  {                                                                         \
    const int s_ = (S);                                                     \
    const int t_ = TT - 2 - s_;                                             \
    { /* deferred store of beta row t_+1 */                                 \
      unsigned short* op_ = outh + rown + (size_t)(t_ + 1) * KK + jo0;      \
      _Pragma("unroll") for (int mt = 0; mt < 4; ++mt)                      \
          *(u2v*)(op_ + 16 * mt) = mku2(qst[2 * mt], qst[2 * mt + 1]);      \
      float mm_ = fmaxf(mloc, __shfl_xor(mloc, 16));                        \
      mm_ = fmaxf(mm_, __shfl_xor(mm_, 32));                                \
      if (l < 16) sm.smax[CUR][n][w] = mm_;                                 \
    }                                                                       \
    RSCALE(CUR, rs_)                                                        \
    const f4 ec0 = EU[0], ec1 = EU[1], ec2 = EU[2], ec3 = EU[3];            \
    const int o2_ = sm.obs4[n][t_ >= 2 ? t_ - 2 : 0];                       \
    emis4(o2_, EU);                                                         \
    f4 acc[4];                                                              \
    MFMA4(CUR, acc)                                                         \
    const f4 ecs[4] = {ec0, ec1, ec2, ec3};                                 \
    mloc = 0.f;                                                             \
    _Pragma("unroll") for (int mt = 0; mt < 4; ++mt) {                      \
      const f4 bsc = acc[mt] * rs_;           /* scaled beta_t */           \
      const f4 yw = bsc * ecs[mt];            /* staged w_t */              \
      qst[2 * mt] = pkbf(bsc[0], bsc[1]);                                   \
      qst[2 * mt + 1] = pkbf(bsc[2], bsc[3]);                               \
      pst[2 * mt] = pkbf(yw[0], yw[1]);                                     \
      pst[2 * mt + 1] = pkbf(yw[2], yw[3]);                                 \
      mloc = fmaxf(mloc, fmax4(yw));                                        \
    }                                                                       \
    STAGE(CUR, pst)                                                         \
    bar_lds();                                                              \
  }

#pragma unroll 1
    for (int s = 0; s < TT - 2; s += 2) {
      STEPB(s, 0, eA)
      STEPB(s + 1, 1, eB)
    }
    STEPB(TT - 2, 0, eA)  // s = 510 -> t = 0
    {                     // final deferred row 0
      unsigned short* op = outh + rown + jo0;
#pragma unroll
      for (int mt = 0; mt < 4; ++mt)
        *(u2v*)(op + 16 * mt) = mku2(qst[2 * mt], qst[2 * mt + 1]);
    }
#undef STEPB
  }
#undef MFMA4
#undef SHADOW
#undef RSCALE
#undef STAGE
}

__global__ __launch_bounds__(256, 1) void hmm4_comb(
    const float* __restrict__ lpi, const float* __restrict__ lA,
    const float* __restrict__ ebT, const int* __restrict__ obs,
    unsigned short* __restrict__ aws, unsigned short* __restrict__ bws) {
  __shared__ Sm4 sm;
  if (blockIdx.x < NBLK)
    body4<0>(sm, blockIdx.x, lpi, lA, ebT, obs, aws);
  else
    body4<2>(sm, blockIdx.x - NBLK, lpi, lA, ebT, obs, bws);
}

// ================== R12 8-wave kernels (fallback tiers) ==================
struct SmemT {
  unsigned short obs_s[SPB][520];
  b8 xfrag[2][8][64];
  float smax[2][160];
};

template <int MODE, bool TRANS, bool H16>
__device__ __forceinline__ void hmm_body(
    SmemT& sm, int blk, const float* __restrict__ lpi,
    const float* __restrict__ lA, const float* __restrict__ lB,
    const float* __restrict__ ebT, const int* __restrict__ obs,
    float* __restrict__ gout, unsigned short* __restrict__ outh) {
  const int n0 = blk * SPB;
  const int tid = threadIdx.x;
  const int w = tid >> 6;
  const int l = tid & 63;
  const int n = l & 15;
  const int q = l >> 4;
  const int j0 = 32 * w + 4 * q;

  for (int i = tid; i < SPB * TT; i += 512)
    sm.obs_s[i >> 9][i & 511] = (unsigned short)obs[(size_t)n0 * TT + i];

  b8 afrag[2][8];
#pragma unroll
  for (int mt = 0; mt < 2; ++mt) {
    const int m = (2 * w + mt) * 16 + n;
#pragma unroll
    for (int kc = 0; kc < 8; ++kc) {
      u4v tmp;
#pragma unroll
      for (int ep = 0; ep < 4; ++ep) {
        const int k = kc * 32 + q * 8 + 2 * ep;
        float v0, v1;
        if (MODE == 0) {
          v0 = lA[(size_t)k * KK + m];
          v1 = lA[(size_t)(k + 1) * KK + m];
        } else {
          v0 = lA[(size_t)m * KK + k];
          v1 = lA[(size_t)m * KK + k + 1];
        }
        tmp[ep] = (u32)f2bf_rne(exp2f(v0 * LOG2E)) |
                  ((u32)f2bf_rne(exp2f(v1 * LOG2E)) << 16);
      }
      afrag[mt][kc] = __builtin_bit_cast(b8, tmp);
    }
  }
  const int lam0 = (q >> 1) * 16 + n;
  const int e0 = (q & 1) * 4;
  __syncthreads();

  auto emis = [&](int te, f4& ea, f4& eb) {
    const int o = sm.obs_s[n][te];
    if constexpr (TRANS) {
      const float* er = ebT + (size_t)o * KK + j0;
      ea = *(const f4*)er;
      eb = *(const f4*)(er + 16);
    } else {
#pragma unroll
      for (int r = 0; r < 4; ++r) {
        ea[r] = exp2f(lB[(size_t)(j0 + r) * VV + o] * LOG2E);
        eb[r] = exp2f(lB[(size_t)(j0 + 16 + r) * VV + o] * LOG2E);
      }
    }
  };
  auto stage_write = [&](const u32 p[4], const float yv[8], int dst) {
    *(u2v*)((unsigned short*)&sm.xfrag[dst][w][lam0] + e0) = mku2(p[0], p[1]);
    *(u2v*)((unsigned short*)&sm.xfrag[dst][w][lam0 + 32] + e0) =
        mku2(p[2], p[3]);
    float m = fmaxf(fmaxf(fmaxf(yv[0], yv[1]), fmaxf(yv[2], yv[3])),
                    fmaxf(fmaxf(yv[4], yv[5]), fmaxf(yv[6], yv[7])));
    m = fmaxf(m, __shfl_xor(m, 16));
    m = fmaxf(m, __shfl_xor(m, 32));
    if (l < 16) sm.smax[dst][l * 9 + w] = m;
  };
  auto mfma_step = [&](int cur, f4& o0, f4& o1) {
    b8 bfr[8];
#pragma unroll
    for (int kc = 0; kc < 8; ++kc) bfr[kc] = sm.xfrag[cur][kc][l];
    f4 a0a = {0.f, 0.f, 0.f, 0.f}, a0b = a0a, a1a = a0a, a1b = a0a;
#pragma unroll
    for (int kc = 0; kc < 4; ++kc) {
      a0a = __builtin_amdgcn_mfma_f32_16x16x32_bf16(afrag[0][kc], bfr[kc],
                                                    a0a, 0, 0, 0);
      a1a = __builtin_amdgcn_mfma_f32_16x16x32_bf16(afrag[1][kc], bfr[kc],
                                                    a1a, 0, 0, 0);
    }
#pragma unroll
    for (int kc = 4; kc < 8; ++kc) {
      a0b = __builtin_amdgcn_mfma_f32_16x16x32_bf16(afrag[0][kc], bfr[kc],
                                                    a0b, 0, 0, 0);
      a1b = __builtin_amdgcn_mfma_f32_16x16x32_bf16(afrag[1][kc], bfr[kc],
                                                    a1b, 0, 0, 0);
    }
    o0 = a0a + a0b;
    o1 = a1a + a1b;
  };
  auto rscale = [&](int cur) -> float {
    float mm = sm.smax[cur][n * 9];
#pragma unroll
    for (int ww = 1; ww < 8; ++ww) mm = fmaxf(mm, sm.smax[cur][n * 9 + ww]);
    return __builtin_amdgcn_rcpf(fmaxf(mm, 1e-30f));
  };

  if (tid < 320) ((float*)sm.smax)[tid] = 1.0f;
  __syncthreads();

  if (MODE == 0) {
    f4 ea, eb;
    emis(0, ea, eb);
    float y0[8];
#pragma unroll
    for (int r = 0; r < 8; ++r) {
      const int jr = j0 + 16 * (r >> 2) + (r & 3);
      y0[r] = exp2f(lpi[jr] * LOG2E) * ((r < 4) ? ea[r] : eb[r - 4]);
    }
    u32 p[4] = {pkbf(y0[0], y0[1]), pkbf(y0[2], y0[3]), pkbf(y0[4], y0[5]),
                pkbf(y0[6], y0[7])};
    stage_write(p, y0, 0);
    {
      float* op = gout + ((size_t)(n0 + n) * TT + 0) * KK + j0;
      f4 v0, v1;
#pragma unroll
      for (int r = 0; r < 4; ++r) { v0[r] = y0[r]; v1[r] = y0[4 + r]; }
      *(f4*)op = v0;
      *(f4*)(op + 16) = v1;
    }
    bar_lds();
    f4 eca, ecb;
    emis(1, eca, ecb);
#pragma unroll 1
    for (int t = 0; t < TT - 1; ++t) {
      const int cur = t & 1;
      f4 pa, pb;
      emis(t + 2 < TT ? t + 2 : TT - 1, pa, pb);
      const float rs = rscale(cur);
      f4 acc0, acc1;
      mfma_step(cur, acc0, acc1);
      float yv[8];
#pragma unroll
      for (int r = 0; r < 8; ++r) {
        const float e = (r < 4) ? eca[r] : ecb[r - 4];
        const float D = (r < 4) ? acc0[r] : acc1[r - 4];
        yv[r] = D * e * rs;
      }
      u32 pp[4] = {pkbf(yv[0], yv[1]), pkbf(yv[2], yv[3]), pkbf(yv[4], yv[5]),
                   pkbf(yv[6], yv[7])};
      stage_write(pp, yv, cur ^ 1);
      {
        float* op = gout + ((size_t)(n0 + n) * TT + t + 1) * KK + j0;
        f4 v0, v1;
#pragma unroll
        for (int r = 0; r < 4; ++r) { v0[r] = yv[r]; v1[r] = yv[4 + r]; }
        *(f4*)op = v0;
        *(f4*)(op + 16) = v1;
      }
      bar_lds();
      eca = pa;
      ecb = pb;
    }
  } else {
    f4 ea, eb;
    emis(TT - 1, ea, eb);
    float y0[8];
#pragma unroll
    for (int r = 0; r < 8; ++r) y0[r] = (r < 4) ? ea[r] : eb[r - 4];
    u32 p[4] = {pkbf(y0[0], y0[1]), pkbf(y0[2], y0[3]), pkbf(y0[4], y0[5]),
                pkbf(y0[6], y0[7])};
    stage_write(p, y0, 0);
    bar_lds();
    f4 eca, ecb;
    emis(TT - 2, eca, ecb);
    f4 aa = {0.f, 0.f, 0.f, 0.f}, ab = aa;
    {
      const float* ar = gout + ((size_t)(n0 + n) * TT + (TT - 2)) * KK + j0;
      aa = *(const f4*)ar;
      ab = *(const f4*)(ar + 16);
    }
#pragma unroll 1
    for (int t = TT - 2; t >= 0; --t) {
      const int cur = (TT - 2 - t) & 1;
      const int tp = t > 0 ? t - 1 : 0;
      f4 pa, pb;
      emis(tp, pa, pb);
      f4 naa = {0.f, 0.f, 0.f, 0.f}, nab = naa;
      if (t > 0) {
        const float* ar = gout + ((size_t)(n0 + n) * TT + tp) * KK + j0;
        naa = *(const f4*)ar;
        nab = *(const f4*)(ar + 16);
      }
      const float rs = rscale(cur);
      f4 acc0, acc1;
      mfma_step(cur, acc0, acc1);
      float yv[8];
#pragma unroll
      for (int r = 0; r < 8; ++r) {
        const float bvr = (r < 4) ? acc0[r] : acc1[r - 4];
        const float e = (r < 4) ? eca[r] : ecb[r - 4];
        yv[r] = bvr * e * rs;
      }
      u32 pp[4] = {pkbf(yv[0], yv[1]), pkbf(yv[2], yv[3]), pkbf(yv[4], yv[5]),
                   pkbf(yv[6], yv[7])};
      stage_write(pp, yv, cur ^ 1);
      {
        f4 g0, g1;
#pragma unroll
        for (int r = 0; r < 4; ++r) {
          g0[r] = aa[r] * acc0[r];
          g1[r] = ab[r] * acc1[r];
        }
        float* op = gout + ((size_t)(n0 + n) * TT + t) * KK + j0;
        *(f4*)op = g0;
        *(f4*)(op + 16) = g1;
      }
      bar_lds();
      eca = pa;
      ecb = pb;
      aa = naa;
      ab = nab;
    }
  }
}

template <int MODE, bool TRANS>
__global__ __launch_bounds__(512, 1) void hmm_one(
    const float* __restrict__ lpi, const float* __restrict__ lA,
    const float* __restrict__ lB, const float* __restrict__ ebT,
    const int* __restrict__ obs, float* __restrict__ gout) {
  __shared__ SmemT sm;
  hmm_body<MODE, TRANS, false>(sm, blockIdx.x, lpi, lA, lB, ebT, obs, gout,
                               nullptr);
}

// ============================ streaming passes ============================
__global__ __launch_bounds__(256) void expT(const float* __restrict__ lB,
                                            float* __restrict__ ebT) {
#pragma unroll 1
  for (int v = blockIdx.x; v < VV; v += gridDim.x)
    for (int k = threadIdx.x; k < KK; k += 256)
      ebT[(size_t)v * KK + k] = exp2f(lB[(size_t)k * VV + v] * LOG2E);
}

__global__ __launch_bounds__(256) void gamma_mul16(
    float* __restrict__ gout, const unsigned short* __restrict__ aw,
    const unsigned short* __restrict__ bw) {
  const int wave = blockIdx.x * 4 + (threadIdx.x >> 6);
  const int c = threadIdx.x & 63;
  const int stride = gridDim.x * 4;
#pragma unroll 1
  for (int row = wave; row < NB * TT; row += stride) {
    const size_t base = (size_t)row * KK + c * 4;
    const u2v ua = *(const u2v*)(aw + base);
    const u2v ub = *(const u2v*)(bw + base);
    f4 v;
    v[0] = __uint_as_float(ua[0] << 16) * __uint_as_float(ub[0] << 16);
    v[1] = __uint_as_float(ua[0] & 0xFFFF0000u) *
           __uint_as_float(ub[0] & 0xFFFF0000u);
    v[2] = __uint_as_float(ua[1] << 16) * __uint_as_float(ub[1] << 16);
    v[3] = __uint_as_float(ua[1] & 0xFFFF0000u) *
           __uint_as_float(ub[1] & 0xFFFF0000u);
#pragma unroll
    for (int r = 0; r < 4; ++r) v[r] = fmaxf(v[r], 1e-37f);
    float s = (v[0] + v[1]) + (v[2] + v[3]);
#pragma unroll
    for (int d = 1; d < 64; d <<= 1) s += __shfl_xor(s, d);
    const float lg = __log2f(s);
    f4 o;
    o[0] = (__log2f(v[0]) - lg) * LN2;
    o[1] = (__log2f(v[1]) - lg) * LN2;
    o[2] = (__log2f(v[2]) - lg) * LN2;
    o[3] = (__log2f(v[3]) - lg) * LN2;
    *(f4*)(gout + base) = o;
  }
}

__global__ __launch_bounds__(256) void gamma_norm(float* __restrict__ gout) {
  const int wave = blockIdx.x * 4 + (threadIdx.x >> 6);
  const int c = threadIdx.x & 63;
  const int stride = gridDim.x * 4;
#pragma unroll 1
  for (int row = wave; row < NB * TT; row += stride) {
    float* p = gout + (size_t)row * KK + c * 4;
    const f4 v = *(const f4*)p;
    float s = (v[0] + v[1]) + (v[2] + v[3]);
#pragma unroll
    for (int d = 1; d < 64; d <<= 1) s += __shfl_xor(s, d);
    const float lg = __log2f(s);
    f4 o;
    o[0] = (__log2f(v[0]) - lg) * LN2;
    o[1] = (__log2f(v[1]) - lg) * LN2;
    o[2] = (__log2f(v[2]) - lg) * LN2;
    o[3] = (__log2f(v[3]) - lg) * LN2;
    *(f4*)p = o;
  }
}

extern "C" void kernel_launch(void* const* d_in, const int* in_sizes, int n_in,
                              void* d_out, int out_size, void* d_ws, size_t ws_size,
                              hipStream_t stream) {
  const float* lpi = (const float*)d_in[0];
  const float* lA = (const float*)d_in[1];
  const float* lB = (const float*)d_in[2];
  const int* obs = (const int*)d_in[3];
  float* gout = (float*)d_out;

  const size_t EBT_B = (size_t)VV * KK * sizeof(float);       // 4 MB
  const size_t H16_B = (size_t)NB * TT * KK * sizeof(short);  // 67 MB
  float* ebT = (float*)d_ws;
  unsigned short* aws = (unsigned short*)((char*)d_ws + EBT_B);
  unsigned short* bws = (unsigned short*)((char*)d_ws + EBT_B + H16_B);

  if (ws_size >= EBT_B + 2 * H16_B) {
    expT<<<2048, 256, 0, stream>>>(lB, ebT);
    hmm4_comb<<<2 * NBLK, 256, 0, stream>>>(lpi, lA, ebT, obs, aws, bws);
    gamma_mul16<<<2048, 256, 0, stream>>>(gout, aws, bws);
  } else if (ws_size >= EBT_B) {
    expT<<<2048, 256, 0, stream>>>(lB, ebT);
    hmm_one<0, true><<<NBLK, 512, 0, stream>>>(lpi, lA, lB, ebT, obs, gout);
    hmm_one<1, true><<<NBLK, 512, 0, stream>>>(lpi, lA, lB, ebT, obs, gout);
    gamma_norm<<<2048, 256, 0, stream>>>(gout);
  } else {
    hmm_one<0, false><<<NBLK, 512, 0, stream>>>(lpi, lA, lB, nullptr, obs,
                                                gout);
    hmm_one<1, false><<<NBLK, 512, 0, stream>>>(lpi, lA, lB, nullptr, obs,
                                                gout);
    gamma_norm<<<2048, 256, 0, stream>>>(gout);
  }
}

// Round 10
// 313.204 us; speedup vs baseline: 2.2404x; 2.2070x over previous
//
#include <hip/hip_runtime.h>
#include <stdint.h>

// Baum-Welch forward-backward posteriors (log_gamma), MI355X gfx950.
//
// R13 -> R14: TIME-PARALLEL chunked recurrence.
//  - R5-R13: every step-internal variant (waves, barriers, scale scheme,
//    dtype, store path) sat at 2300-2700 cy/step -> the serial step count,
//    not the step body, is the wall. 32 blocks left 224 CUs idle.
//  - Positive-matrix contraction (Birkhoff): diag(b) factors are Hilbert-
//    metric isometries; A^T (softmax rows, near-rank-1) contracts any
//    start direction ~0.1-0.3x/step -> 64-step warmup error < 1e-30.
//    gamma normalizes per (n,t), so per-chunk arbitrary scales cancel.
//  - 8 chunks x 64 rows per direction; chain = 64 warmup + 64 output steps
//    (127 steps; fwd chunk 0 / bwd chunk 7 start exact). 256 blocks
//    (2 dir x 8 chunks x 16 seq-groups) -> all CUs busy, serial depth 4x lower.
//  - Step body = R13's proven bf16-MFMA machinery (deferred-by-2 scale,
//    deferred stores, one lgkm-only barrier), runtime `cur` (LDS-indexed).
//  - Fallback tiers (small ws): R12's full-length kernels, unchanged.

#define NB 256
#define TT 512
#define KK 256
#define VV 4096
#define SPB 16            // sequences per block
#define NBLK (NB / SPB)   // 16 seq-groups
#define CL 64             // chunk length (rows written per chunk)
#define CW 64             // warmup steps
#define NCH (TT / CL)     // 8 chunks per direction
#define LOG2E 1.44269504088896f
#define LN2 0.693147180559945f

typedef float f4 __attribute__((ext_vector_type(4)));
typedef short b8 __attribute__((ext_vector_type(8)));
typedef unsigned int u32;
typedef u32 u2v __attribute__((ext_vector_type(2)));
typedef u32 u4v __attribute__((ext_vector_type(4)));

__device__ __forceinline__ void bar_lds() {
  asm volatile("s_waitcnt lgkmcnt(0)" ::: "memory");
  __builtin_amdgcn_s_barrier();
}

__device__ __forceinline__ unsigned short f2bf_rne(float x) {
  u32 u = __float_as_uint(x);
  return (unsigned short)((u + 0x7FFFu + ((u >> 16) & 1u)) >> 16);
}
// pack two positive floats to 2xbf16 (round-half-up) in one v_perm each.
__device__ __forceinline__ u32 pkbf(float lo, float hi) {
  return __builtin_amdgcn_perm(__float_as_uint(hi) + 0x8000u,
                               __float_as_uint(lo) + 0x8000u, 0x07060302u);
}
__device__ __forceinline__ u2v mku2(u32 a, u32 b) {
  u2v v; v[0] = a; v[1] = b; return v;
}
__device__ __forceinline__ float fmax4(const f4& v) {
  return fmaxf(fmaxf(v[0], v[1]), fmaxf(v[2], v[3]));
}

// ==================== chunked 4-wave MFMA recurrence ====================
struct Sm4c {
  unsigned short obs4[SPB][136];       // 4.4 KB chunk obs window
  b8 xfrag[2][8][64];                  // 16 KB ping-pong B fragments
  __align__(16) float smax[2][16][4];  // deferred per-seq max partials
};

// MODE 0: forward chunk -> bf16 scaled-alpha rows [wlo, wlo+CL) of outh.
// MODE 2: backward chunk -> bf16 scaled-beta rows [wlo, wlo+CL) (chunk 7
//         also writes row 511 = 1).
template <int MODE>
__device__ __forceinline__ void body4c(Sm4c& sm, int n0, int c,
                                       const float* __restrict__ lpi,
                                       const float* __restrict__ lA,
                                       const float* __restrict__ ebT,
                                       const int* __restrict__ obs,
                                       unsigned short* __restrict__ outh) {
  const int tid = threadIdx.x;  // 0..255
  const int w = tid >> 6;       // wave 0..3: owns states [64w, 64w+64)
  const int l = tid & 63;
  const int n = l & 15;         // sequence slot
  const int q = l >> 4;         // 0..3
  const int jo0 = 64 * w + 4 * q;

  // Chunk ranges.
  const int wlo = c * CL;
  int t0 = 0, tEnd = 0, tS = 0, whi = 0, base, tmax;
  if (MODE == 0) {
    tEnd = wlo + CL - 1;
    t0 = (c == 0) ? 0 : wlo - CW;
    base = t0;
    tmax = tEnd;
  } else {
    whi = wlo + CL;
    tS = whi + CW - 1;
    if (tS > TT - 1) tS = TT - 1;
    base = wlo;
    tmax = tS;
  }
  const int win = tmax - base + 1;  // <= 128

  for (int i = tid; i < SPB * 128; i += 256) {
    const int s = i >> 7, k = i & 127;
    if (k < win)
      sm.obs4[s][k] = (unsigned short)obs[(size_t)(n0 + s) * TT + base + k];
  }

  // A fragments: tile = 4w+mt, m = 16*tile + n, k = kc*32 + q*8 + e.
  // fwd: expA[k][m] (A^T); bwd: expA[m][k] (A).
  b8 af[4][8];
#pragma unroll
  for (int mt = 0; mt < 4; ++mt) {
    const int m = 16 * (4 * w + mt) + n;
#pragma unroll
    for (int kc = 0; kc < 8; ++kc) {
      u4v tmp;
#pragma unroll
      for (int ep = 0; ep < 4; ++ep) {
        const int k = kc * 32 + q * 8 + 2 * ep;
        float v0, v1;
        if (MODE == 0) {
          v0 = lA[(size_t)k * KK + m];
          v1 = lA[(size_t)(k + 1) * KK + m];
        } else {
          v0 = lA[(size_t)m * KK + k];
          v1 = lA[(size_t)m * KK + k + 1];
        }
        tmp[ep] = pkbf(exp2f(v0 * LOG2E), exp2f(v1 * LOG2E));
      }
      af[mt][kc] = __builtin_bit_cast(b8, tmp);
    }
  }

  // Staging map (R10-verified): plane kc = tile>>1;
  // ushort index = 8*(n + 16*(q>>1) + 32*(tile&1)) + 4*(q&1).
  int usb[4];
#pragma unroll
  for (int mt = 0; mt < 4; ++mt) {
    const int tile = 4 * w + mt;
    usb[mt] = 8 * (n + 16 * (q >> 1) + 32 * (tile & 1)) + 4 * (q & 1);
  }
  const int kcp[4] = {(4 * w) >> 1, (4 * w) >> 1, (4 * w + 2) >> 1,
                      (4 * w + 2) >> 1};

  if (tid < 128) ((float*)sm.smax)[tid] = 1.0f;  // seed both slots
  __syncthreads();

  const size_t rown = (size_t)(n0 + n) * TT * KK;
  u32 pst[8], qst[8];
  float mloc = 0.f;
  f4 eA[4], eB[4];
  int cur = 0;

  auto emis4 = [&](int o, f4 e[4]) {
    const float* er = ebT + (size_t)o * KK + jo0;
#pragma unroll
    for (int mt = 0; mt < 4; ++mt) e[mt] = *(const f4*)(er + 16 * mt);
  };

#define MFMA4(ACC)                                                          \
  {                                                                         \
    b8 bfr[8];                                                              \
    _Pragma("unroll") for (int kc = 0; kc < 8; ++kc) bfr[kc] =              \
        sm.xfrag[cur][kc][l];                                               \
    _Pragma("unroll") for (int mt = 0; mt < 4; ++mt) {                      \
      f4 ca = {0.f, 0.f, 0.f, 0.f}, cb = ca;                                \
      _Pragma("unroll") for (int kc = 0; kc < 4; ++kc) ca =                 \
          __builtin_amdgcn_mfma_f32_16x16x32_bf16(af[mt][kc], bfr[kc], ca,  \
                                                  0, 0, 0);                 \
      _Pragma("unroll") for (int kc = 4; kc < 8; ++kc) cb =                 \
          __builtin_amdgcn_mfma_f32_16x16x32_bf16(af[mt][kc], bfr[kc], cb,  \
                                                  0, 0, 0);                 \
      ACC[mt] = ca + cb;                                                    \
    }                                                                       \
  }

#define STAGE(P)                                                            \
  _Pragma("unroll") for (int mt = 0; mt < 4; ++mt)                          \
      *(u2v*)((unsigned short*)&sm.xfrag[cur ^ 1][kcp[mt]][0] + usb[mt]) =  \
          mku2(P[2 * mt], P[2 * mt + 1]);

#define SMWR()                                                              \
  {                                                                         \
    float mm_ = fmaxf(mloc, __shfl_xor(mloc, 16));                          \
    mm_ = fmaxf(mm_, __shfl_xor(mm_, 32));                                  \
    if (l < 16) sm.smax[cur][n][w] = mm_;                                   \
  }

#define RSCALE(RS)                                                          \
  const f4 sm4_ = *(const f4*)&sm.smax[cur ^ 1][n][0];                      \
  const float RS = __builtin_amdgcn_rcpf(fmaxf(fmax4(sm4_), 1e-30f));

#define STEPF(T_, EU)                                                       \
  {                                                                         \
    const int tt_ = (T_);                                                   \
    if (tt_ >= wlo) { /* deferred store of row tt_ */                       \
      unsigned short* op_ = outh + rown + (size_t)tt_ * KK + jo0;           \
      _Pragma("unroll") for (int mt = 0; mt < 4; ++mt)                      \
          *(u2v*)(op_ + 16 * mt) = mku2(pst[2 * mt], pst[2 * mt + 1]);      \
    }                                                                       \
    SMWR()                                                                  \
    RSCALE(rs_)                                                             \
    const f4 ec0 = EU[0], ec1 = EU[1], ec2 = EU[2], ec3 = EU[3];            \
    const int o3_ = sm.obs4[n][(tt_ + 3 <= tEnd ? tt_ + 3 : tEnd) - base];  \
    emis4(o3_, EU);                                                         \
    f4 acc[4];                                                              \
    MFMA4(acc)                                                              \
    const f4 ecs_[4] = {ec0, ec1, ec2, ec3};                                \
    mloc = 0.f;                                                             \
    _Pragma("unroll") for (int mt = 0; mt < 4; ++mt) {                      \
      const f4 y_ = acc[mt] * (ecs_[mt] * rs_);                             \
      pst[2 * mt] = pkbf(y_[0], y_[1]);                                     \
      pst[2 * mt + 1] = pkbf(y_[2], y_[3]);                                 \
      mloc = fmaxf(mloc, fmax4(y_));                                        \
    }                                                                       \
    STAGE(pst)                                                              \
    bar_lds();                                                              \
    cur ^= 1;                                                               \
  }

#define STEPB(T_, EU)                                                       \
  {                                                                         \
    const int tt_ = (T_);                                                   \
    if (tt_ + 1 < whi) { /* deferred store of beta row tt_+1 */             \
      unsigned short* op_ = outh + rown + (size_t)(tt_ + 1) * KK + jo0;     \
      _Pragma("unroll") for (int mt = 0; mt < 4; ++mt)                      \
          *(u2v*)(op_ + 16 * mt) = mku2(qst[2 * mt], qst[2 * mt + 1]);      \
    }                                                                       \
    SMWR()                                                                  \
    RSCALE(rs_)                                                             \
    const f4 ec0 = EU[0], ec1 = EU[1], ec2 = EU[2], ec3 = EU[3];            \
    const int o2_ = sm.obs4[n][(tt_ >= wlo + 2 ? tt_ - 2 : wlo) - base];    \
    emis4(o2_, EU);                                                         \
    f4 acc[4];                                                              \
    MFMA4(acc)                                                              \
    const f4 ecs_[4] = {ec0, ec1, ec2, ec3};                                \
    mloc = 0.f;                                                             \
    _Pragma("unroll") for (int mt = 0; mt < 4; ++mt) {                      \
      const f4 bsc_ = acc[mt] * rs_;        /* scaled beta_t */             \
      const f4 yw_ = bsc_ * ecs_[mt];       /* staged w_t */                \
      qst[2 * mt] = pkbf(bsc_[0], bsc_[1]);                                 \
      qst[2 * mt + 1] = pkbf(bsc_[2], bsc_[3]);                             \
      pst[2 * mt] = pkbf(yw_[0], yw_[1]);                                   \
      pst[2 * mt + 1] = pkbf(yw_[2], yw_[3]);                               \
      mloc = fmaxf(mloc, fmax4(yw_));                                       \
    }                                                                       \
    STAGE(pst)                                                              \
    bar_lds();                                                              \
    cur ^= 1;                                                               \
  }

  if (MODE == 0) {
    // ---- forward chunk: init at t0 (exact for c==0, else uniform) ----
    {
      f4 e0v[4];
      emis4(sm.obs4[n][0], e0v);  // t0 - base = 0
      mloc = 0.f;
#pragma unroll
      for (int mt = 0; mt < 4; ++mt) {
        f4 u;
        if (c == 0) {
          const f4 pi4 = *(const f4*)(lpi + jo0 + 16 * mt);
#pragma unroll
          for (int r = 0; r < 4; ++r)
            u[r] = exp2f(pi4[r] * LOG2E) * e0v[mt][r];
        } else {
          u = e0v[mt];  // uniform prior x emission
        }
        pst[2 * mt] = pkbf(u[0], u[1]);
        pst[2 * mt + 1] = pkbf(u[2], u[3]);
        mloc = fmaxf(mloc, fmax4(u));
      }
      cur = 1;
      STAGE(pst)  // -> xfrag[0]
      cur = 0;
      emis4(sm.obs4[n][t0 + 1 - base], eA);
      emis4(sm.obs4[n][t0 + 2 - base], eB);
      bar_lds();
    }
    STEPF(t0, eA)  // count tEnd-t0 is odd (63 or 127): peel one
#pragma unroll 1
    for (int T = t0 + 1; T <= tEnd - 2; T += 2) {
      STEPF(T, eB)
      STEPF(T + 1, eA)
    }
    {  // final row tEnd
      unsigned short* op = outh + rown + (size_t)tEnd * KK + jo0;
#pragma unroll
      for (int mt = 0; mt < 4; ++mt)
        *(u2v*)(op + 16 * mt) = mku2(pst[2 * mt], pst[2 * mt + 1]);
    }
  } else {
    // ---- backward chunk: init at tS (exact beta=1 for tS==511) ----
    {
      f4 e0v[4];
      emis4(sm.obs4[n][tS - base], e0v);
      mloc = 0.f;
#pragma unroll
      for (int mt = 0; mt < 4; ++mt) {
        pst[2 * mt] = pkbf(e0v[mt][0], e0v[mt][1]);
        pst[2 * mt + 1] = pkbf(e0v[mt][2], e0v[mt][3]);
        mloc = fmaxf(mloc, fmax4(e0v[mt]));
        qst[2 * mt] = 0x3F803F80u;  // beta(tS) = 1 (2xbf16)
        qst[2 * mt + 1] = 0x3F803F80u;
      }
      cur = 1;
      STAGE(pst)  // staged w_tS -> xfrag[0]
      cur = 0;
      emis4(sm.obs4[n][tS - 1 - base], eA);
      emis4(sm.obs4[n][tS - 2 - base], eB);
      bar_lds();
    }
    STEPB(tS - 1, eA)  // count tS-wlo is odd (63 or 127): peel one
#pragma unroll 1
    for (int T = tS - 2; T >= wlo + 1; T -= 2) {
      STEPB(T, eB)
      STEPB(T - 1, eA)
    }
    {  // final row wlo
      unsigned short* op = outh + rown + (size_t)wlo * KK + jo0;
#pragma unroll
      for (int mt = 0; mt < 4; ++mt)
        *(u2v*)(op + 16 * mt) = mku2(qst[2 * mt], qst[2 * mt + 1]);
    }
  }
#undef MFMA4
#undef STAGE
#undef SMWR
#undef RSCALE
#undef STEPF
#undef STEPB
}

__global__ __launch_bounds__(256, 1) void hmm4_chunks(
    const float* __restrict__ lpi, const float* __restrict__ lA,
    const float* __restrict__ ebT, const int* __restrict__ obs,
    unsigned short* __restrict__ aws, unsigned short* __restrict__ bws) {
  __shared__ Sm4c sm;
  const int bid = blockIdx.x;
  const int sg = bid & 15;
  const int c = (bid >> 4) & 7;
  if (bid < NBLK * NCH)
    body4c<0>(sm, sg * SPB, c, lpi, lA, ebT, obs, aws);
  else
    body4c<2>(sm, sg * SPB, c, lpi, lA, ebT, obs, bws);
}

// ================== R12 8-wave kernels (fallback tiers) ==================
struct SmemT {
  unsigned short obs_s[SPB][520];
  b8 xfrag[2][8][64];
  float smax[2][160];
};

template <int MODE, bool TRANS>
__device__ __forceinline__ void hmm_body(
    SmemT& sm, int blk, const float* __restrict__ lpi,
    const float* __restrict__ lA, const float* __restrict__ lB,
    const float* __restrict__ ebT, const int* __restrict__ obs,
    float* __restrict__ gout) {
  const int n0 = blk * SPB;
  const int tid = threadIdx.x;
  const int w = tid >> 6;
  const int l = tid & 63;
  const int n = l & 15;
  const int q = l >> 4;
  const int j0 = 32 * w + 4 * q;

  for (int i = tid; i < SPB * TT; i += 512)
    sm.obs_s[i >> 9][i & 511] = (unsigned short)obs[(size_t)n0 * TT + i];

  b8 afrag[2][8];
#pragma unroll
  for (int mt = 0; mt < 2; ++mt) {
    const int m = (2 * w + mt) * 16 + n;
#pragma unroll
    for (int kc = 0; kc < 8; ++kc) {
      u4v tmp;
#pragma unroll
      for (int ep = 0; ep < 4; ++ep) {
        const int k = kc * 32 + q * 8 + 2 * ep;
        float v0, v1;
        if (MODE == 0) {
          v0 = lA[(size_t)k * KK + m];
          v1 = lA[(size_t)(k + 1) * KK + m];
        } else {
          v0 = lA[(size_t)m * KK + k];
          v1 = lA[(size_t)m * KK + k + 1];
        }
        tmp[ep] = (u32)f2bf_rne(exp2f(v0 * LOG2E)) |
                  ((u32)f2bf_rne(exp2f(v1 * LOG2E)) << 16);
      }
      afrag[mt][kc] = __builtin_bit_cast(b8, tmp);
    }
  }
  const int lam0 = (q >> 1) * 16 + n;
  const int e0 = (q & 1) * 4;
  __syncthreads();

  auto emis = [&](int te, f4& ea, f4& eb) {
    const int o = sm.obs_s[n][te];
    if constexpr (TRANS) {
      const float* er = ebT + (size_t)o * KK + j0;
      ea = *(const f4*)er;
      eb = *(const f4*)(er + 16);
    } else {
#pragma unroll
      for (int r = 0; r < 4; ++r) {
        ea[r] = exp2f(lB[(size_t)(j0 + r) * VV + o] * LOG2E);
        eb[r] = exp2f(lB[(size_t)(j0 + 16 + r) * VV + o] * LOG2E);
      }
    }
  };
  auto stage_write = [&](const u32 p[4], const float yv[8], int dst) {
    *(u2v*)((unsigned short*)&sm.xfrag[dst][w][lam0] + e0) = mku2(p[0], p[1]);
    *(u2v*)((unsigned short*)&sm.xfrag[dst][w][lam0 + 32] + e0) =
        mku2(p[2], p[3]);
    float m = fmaxf(fmaxf(fmaxf(yv[0], yv[1]), fmaxf(yv[2], yv[3])),
                    fmaxf(fmaxf(yv[4], yv[5]), fmaxf(yv[6], yv[7])));
    m = fmaxf(m, __shfl_xor(m, 16));
    m = fmaxf(m, __shfl_xor(m, 32));
    if (l < 16) sm.smax[dst][l * 9 + w] = m;
  };
  auto mfma_step = [&](int cur, f4& o0, f4& o1) {
    b8 bfr[8];
#pragma unroll
    for (int kc = 0; kc < 8; ++kc) bfr[kc] = sm.xfrag[cur][kc][l];
    f4 a0a = {0.f, 0.f, 0.f, 0.f}, a0b = a0a, a1a = a0a, a1b = a0a;
#pragma unroll
    for (int kc = 0; kc < 4; ++kc) {
      a0a = __builtin_amdgcn_mfma_f32_16x16x32_bf16(afrag[0][kc], bfr[kc],
                                                    a0a, 0, 0, 0);
      a1a = __builtin_amdgcn_mfma_f32_16x16x32_bf16(afrag[1][kc], bfr[kc],
                                                    a1a, 0, 0, 0);
    }
#pragma unroll
    for (int kc = 4; kc < 8; ++kc) {
      a0b = __builtin_amdgcn_mfma_f32_16x16x32_bf16(afrag[0][kc], bfr[kc],
                                                    a0b, 0, 0, 0);
      a1b = __builtin_amdgcn_mfma_f32_16x16x32_bf16(afrag[1][kc], bfr[kc],
                                                    a1b, 0, 0, 0);
    }
    o0 = a0a + a0b;
    o1 = a1a + a1b;
  };
  auto rscale = [&](int cur) -> float {
    float mm = sm.smax[cur][n * 9];
#pragma unroll
    for (int ww = 1; ww < 8; ++ww) mm = fmaxf(mm, sm.smax[cur][n * 9 + ww]);
    return __builtin_amdgcn_rcpf(fmaxf(mm, 1e-30f));
  };

  if (tid < 320) ((float*)sm.smax)[tid] = 1.0f;
  __syncthreads();

  if (MODE == 0) {
    f4 ea, eb;
    emis(0, ea, eb);
    float y0[8];
#pragma unroll
    for (int r = 0; r < 8; ++r) {
      const int jr = j0 + 16 * (r >> 2) + (r & 3);
      y0[r] = exp2f(lpi[jr] * LOG2E) * ((r < 4) ? ea[r] : eb[r - 4]);
    }
    u32 p[4] = {pkbf(y0[0], y0[1]), pkbf(y0[2], y0[3]), pkbf(y0[4], y0[5]),
                pkbf(y0[6], y0[7])};
    stage_write(p, y0, 0);
    {
      float* op = gout + ((size_t)(n0 + n) * TT + 0) * KK + j0;
      f4 v0, v1;
#pragma unroll
      for (int r = 0; r < 4; ++r) { v0[r] = y0[r]; v1[r] = y0[4 + r]; }
      *(f4*)op = v0;
      *(f4*)(op + 16) = v1;
    }
    bar_lds();
    f4 eca, ecb;
    emis(1, eca, ecb);
#pragma unroll 1
    for (int t = 0; t < TT - 1; ++t) {
      const int cur = t & 1;
      f4 pa, pb;
      emis(t + 2 < TT ? t + 2 : TT - 1, pa, pb);
      const float rs = rscale(cur);
      f4 acc0, acc1;
      mfma_step(cur, acc0, acc1);
      float yv[8];
#pragma unroll
      for (int r = 0; r < 8; ++r) {
        const float e = (r < 4) ? eca[r] : ecb[r - 4];
        const float D = (r < 4) ? acc0[r] : acc1[r - 4];
        yv[r] = D * e * rs;
      }
      u32 pp[4] = {pkbf(yv[0], yv[1]), pkbf(yv[2], yv[3]), pkbf(yv[4], yv[5]),
                   pkbf(yv[6], yv[7])};
      stage_write(pp, yv, cur ^ 1);
      {
        float* op = gout + ((size_t)(n0 + n) * TT + t + 1) * KK + j0;
        f4 v0, v1;
#pragma unroll
        for (int r = 0; r < 4; ++r) { v0[r] = yv[r]; v1[r] = yv[4 + r]; }
        *(f4*)op = v0;
        *(f4*)(op + 16) = v1;
      }
      bar_lds();
      eca = pa;
      ecb = pb;
    }
  } else {
    f4 ea, eb;
    emis(TT - 1, ea, eb);
    float y0[8];
#pragma unroll
    for (int r = 0; r < 8; ++r) y0[r] = (r < 4) ? ea[r] : eb[r - 4];
    u32 p[4] = {pkbf(y0[0], y0[1]), pkbf(y0[2], y0[3]), pkbf(y0[4], y0[5]),
                pkbf(y0[6], y0[7])};
    stage_write(p, y0, 0);
    bar_lds();
    f4 eca, ecb;
    emis(TT - 2, eca, ecb);
    f4 aa = {0.f, 0.f, 0.f, 0.f}, ab = aa;
    {
      const float* ar = gout + ((size_t)(n0 + n) * TT + (TT - 2)) * KK + j0;
      aa = *(const f4*)ar;
      ab = *(const f4*)(ar + 16);
    }
#pragma unroll 1
    for (int t = TT - 2; t >= 0; --t) {
      const int cur = (TT - 2 - t) & 1;
      const int tp = t > 0 ? t - 1 : 0;
      f4 pa, pb;
      emis(tp, pa, pb);
      f4 naa = {0.f, 0.f, 0.f, 0.f}, nab = naa;
      if (t > 0) {
        const float* ar = gout + ((size_t)(n0 + n) * TT + tp) * KK + j0;
        naa = *(const f4*)ar;
        nab = *(const f4*)(ar + 16);
      }
      const float rs = rscale(cur);
      f4 acc0, acc1;
      mfma_step(cur, acc0, acc1);
      float yv[8];
#pragma unroll
      for (int r = 0; r < 8; ++r) {
        const float bvr = (r < 4) ? acc0[r] : acc1[r - 4];
        const float e = (r < 4) ? eca[r] : ecb[r - 4];
        yv[r] = bvr * e * rs;
      }
      u32 pp[4] = {pkbf(yv[0], yv[1]), pkbf(yv[2], yv[3]), pkbf(yv[4], yv[5]),
                   pkbf(yv[6], yv[7])};
      stage_write(pp, yv, cur ^ 1);
      {
        f4 g0, g1;
#pragma unroll
        for (int r = 0; r < 4; ++r) {
          g0[r] = aa[r] * acc0[r];
          g1[r] = ab[r] * acc1[r];
        }
        float* op = gout + ((size_t)(n0 + n) * TT + t) * KK + j0;
        *(f4*)op = g0;
        *(f4*)(op + 16) = g1;
      }
      bar_lds();
      eca = pa;
      ecb = pb;
      aa = naa;
      ab = nab;
    }
  }
}

template <int MODE, bool TRANS>
__global__ __launch_bounds__(512, 1) void hmm_one(
    const float* __restrict__ lpi, const float* __restrict__ lA,
    const float* __restrict__ lB, const float* __restrict__ ebT,
    const int* __restrict__ obs, float* __restrict__ gout) {
  __shared__ SmemT sm;
  hmm_body<MODE, TRANS>(sm, blockIdx.x, lpi, lA, lB, ebT, obs, gout);
}

// ============================ streaming passes ============================
__global__ __launch_bounds__(256) void expT(const float* __restrict__ lB,
                                            float* __restrict__ ebT) {
#pragma unroll 1
  for (int v = blockIdx.x; v < VV; v += gridDim.x)
    for (int k = threadIdx.x; k < KK; k += 256)
      ebT[(size_t)v * KK + k] = exp2f(lB[(size_t)k * VV + v] * LOG2E);
}

__global__ __launch_bounds__(256) void gamma_mul16(
    float* __restrict__ gout, const unsigned short* __restrict__ aw,
    const unsigned short* __restrict__ bw) {
  const int wave = blockIdx.x * 4 + (threadIdx.x >> 6);
  const int c = threadIdx.x & 63;
  const int stride = gridDim.x * 4;
#pragma unroll 1
  for (int row = wave; row < NB * TT; row += stride) {
    const size_t base = (size_t)row * KK + c * 4;
    const u2v ua = *(const u2v*)(aw + base);
    const u2v ub = *(const u2v*)(bw + base);
    f4 v;
    v[0] = __uint_as_float(ua[0] << 16) * __uint_as_float(ub[0] << 16);
    v[1] = __uint_as_float(ua[0] & 0xFFFF0000u) *
           __uint_as_float(ub[0] & 0xFFFF0000u);
    v[2] = __uint_as_float(ua[1] << 16) * __uint_as_float(ub[1] << 16);
    v[3] = __uint_as_float(ua[1] & 0xFFFF0000u) *
           __uint_as_float(ub[1] & 0xFFFF0000u);
#pragma unroll
    for (int r = 0; r < 4; ++r) v[r] = fmaxf(v[r], 1e-37f);
    float s = (v[0] + v[1]) + (v[2] + v[3]);
#pragma unroll
    for (int d = 1; d < 64; d <<= 1) s += __shfl_xor(s, d);
    const float lg = __log2f(s);
    f4 o;
    o[0] = (__log2f(v[0]) - lg) * LN2;
    o[1] = (__log2f(v[1]) - lg) * LN2;
    o[2] = (__log2f(v[2]) - lg) * LN2;
    o[3] = (__log2f(v[3]) - lg) * LN2;
    *(f4*)(gout + base) = o;
  }
}

__global__ __launch_bounds__(256) void gamma_norm(float* __restrict__ gout) {
  const int wave = blockIdx.x * 4 + (threadIdx.x >> 6);
  const int c = threadIdx.x & 63;
  const int stride = gridDim.x * 4;
#pragma unroll 1
  for (int row = wave; row < NB * TT; row += stride) {
    float* p = gout + (size_t)row * KK + c * 4;
    const f4 v = *(const f4*)p;
    float s = (v[0] + v[1]) + (v[2] + v[3]);
#pragma unroll
    for (int d = 1; d < 64; d <<= 1) s += __shfl_xor(s, d);
    const float lg = __log2f(s);
    f4 o;
    o[0] = (__log2f(v[0]) - lg) * LN2;
    o[1] = (__log2f(v[1]) - lg) * LN2;
    o[2] = (__log2f(v[2]) - lg) * LN2;
    o[3] = (__log2f(v[3]) - lg) * LN2;
    *(f4*)p = o;
  }
}

extern "C" void kernel_launch(void* const* d_in, const int* in_sizes, int n_in,
                              void* d_out, int out_size, void* d_ws, size_t ws_size,
                              hipStream_t stream) {
  const float* lpi = (const float*)d_in[0];
  const float* lA = (const float*)d_in[1];
  const float* lB = (const float*)d_in[2];
  const int* obs = (const int*)d_in[3];
  float* gout = (float*)d_out;

  const size_t EBT_B = (size_t)VV * KK * sizeof(float);       // 4 MB
  const size_t H16_B = (size_t)NB * TT * KK * sizeof(short);  // 67 MB
  float* ebT = (float*)d_ws;
  unsigned short* aws = (unsigned short*)((char*)d_ws + EBT_B);
  unsigned short* bws = (unsigned short*)((char*)d_ws + EBT_B + H16_B);

  if (ws_size >= EBT_B + 2 * H16_B) {
    expT<<<2048, 256, 0, stream>>>(lB, ebT);
    hmm4_chunks<<<2 * NBLK * NCH, 256, 0, stream>>>(lpi, lA, ebT, obs, aws,
                                                    bws);
    gamma_mul16<<<2048, 256, 0, stream>>>(gout, aws, bws);
  } else if (ws_size >= EBT_B) {
    expT<<<2048, 256, 0, stream>>>(lB, ebT);
    hmm_one<0, true><<<NBLK, 512, 0, stream>>>(lpi, lA, lB, ebT, obs, gout);
    hmm_one<1, true><<<NBLK, 512, 0, stream>>>(lpi, lA, lB, ebT, obs, gout);
    gamma_norm<<<2048, 256, 0, stream>>>(gout);
  } else {
    hmm_one<0, false><<<NBLK, 512, 0, stream>>>(lpi, lA, lB, nullptr, obs,
                                                gout);
    hmm_one<1, false><<<NBLK, 512, 0, stream>>>(lpi, lA, lB, nullptr, obs,
                                                gout);
    gamma_norm<<<2048, 256, 0, stream>>>(gout);
  }
}